// Round 5
// baseline (23306.367 us; speedup 1.0000x reference)
//
#include <hip/hip_runtime.h>

#define EPS   1e-5f
#define SLOPE 0.01f

// ---------------------------------------------------------------------------
// conv 3x3x3 pad=1 (cross-correlation), cout-register-blocked. (R2-proven shape:
// one ci at a time, xv[VOXB] loads -> COB FMAs. 88 VGPR, no spills.)
// in: [CIN][D][H][W], wt: [Cout][CIN][3][3][3]
// ---------------------------------------------------------------------------
template <int CIN, int COB, int VOXB>
__global__ __launch_bounds__(256) void conv3_v3(const float* __restrict__ in,
                                                const float* __restrict__ wt,
                                                float* __restrict__ out,
                                                int D, int H, int W) {
    const int V = D * H * W;
    __shared__ float wlds[COB * CIN * 27];
    const int co0 = blockIdx.y * COB;
    for (int i = threadIdx.x; i < COB * CIN * 27; i += 256) {
        const int tap = i / (CIN * COB);
        const int r   = i - tap * (CIN * COB);
        const int ci  = r / COB;
        const int co  = r - ci * COB;
        wlds[i] = wt[((size_t)(co0 + co) * CIN + ci) * 27 + tap];
    }
    __syncthreads();

    const int vbase = blockIdx.x * (256 * VOXB) + threadIdx.x;
    int dd[VOXB], hh[VOXB], ww[VOXB];
#pragma unroll
    for (int j = 0; j < VOXB; ++j) {
        const int v = vbase + j * 256;
        ww[j] = v % W;
        hh[j] = (v / W) % H;
        dd[j] = v / (W * H);
    }
    float acc[COB * VOXB];
#pragma unroll
    for (int i = 0; i < COB * VOXB; ++i) acc[i] = 0.f;

#pragma unroll
    for (int kd = 0; kd < 3; ++kd)
#pragma unroll
    for (int kh = 0; kh < 3; ++kh)
#pragma unroll
    for (int kw = 0; kw < 3; ++kw) {
        const int tap = (kd * 3 + kh) * 3 + kw;
        int sp[VOXB]; bool ok[VOXB];
#pragma unroll
        for (int j = 0; j < VOXB; ++j) {
            const int zd = dd[j] + kd - 1, zh = hh[j] + kh - 1, zw = ww[j] + kw - 1;
            ok[j] = ((unsigned)zd < (unsigned)D) & ((unsigned)zh < (unsigned)H) &
                    ((unsigned)zw < (unsigned)W);
            sp[j] = (zd * H + zh) * W + zw;
        }
        const float* wrow = &wlds[tap * CIN * COB];
        for (int ci = 0; ci < CIN; ++ci) {
            float xv[VOXB];
#pragma unroll
            for (int j = 0; j < VOXB; ++j)
                xv[j] = ok[j] ? in[(size_t)ci * V + sp[j]] : 0.f;
            const float* wp = wrow + ci * COB;
#pragma unroll
            for (int co = 0; co < COB; ++co) {
                const float wgt = wp[co];
#pragma unroll
                for (int j = 0; j < VOXB; ++j)
                    acc[co * VOXB + j] = fmaf(xv[j], wgt, acc[co * VOXB + j]);
            }
        }
    }
#pragma unroll
    for (int co = 0; co < COB; ++co)
#pragma unroll
        for (int j = 0; j < VOXB; ++j)
            out[(size_t)(co0 + co) * V + vbase + j * 256] = acc[co * VOXB + j];
}

// ---------------------------------------------------------------------------
// conv 3x3x3 with block-internal ci-split: 64*NS threads = 64 voxel-lanes x NS
// ci-slices (each wave is one slice). Partials reduced through LDS.
// Inner loop is the exact v3 shape (no UNR batching -> no spill).
// ---------------------------------------------------------------------------
template <int CIN, int NS, int COB>
__global__ __launch_bounds__(64 * NS) void conv3_red(const float* __restrict__ in,
                                                     const float* __restrict__ wt,
                                                     float* __restrict__ out,
                                                     int D, int H, int W) {
    const int V = D * H * W;
    constexpr int CPS = CIN / NS;
    __shared__ float wlds[27 * CIN * COB];
    __shared__ float redbuf[NS * COB * 64];
    const int co0   = blockIdx.y * COB;
    const int lane  = threadIdx.x & 63;
    const int slice = threadIdx.x >> 6;
    for (int i = threadIdx.x; i < 27 * CIN * COB; i += 64 * NS) {
        const int tap = i / (CIN * COB);
        const int r   = i - tap * (CIN * COB);
        const int ci  = r / COB;
        const int co  = r - ci * COB;
        wlds[i] = wt[((size_t)(co0 + co) * CIN + ci) * 27 + tap];
    }
    __syncthreads();

    const int v = blockIdx.x * 64 + lane;
    const int w0 = v % W;
    const int h0 = (v / W) % H;
    const int d0 = v / (W * H);

    float acc[COB];
#pragma unroll
    for (int i = 0; i < COB; ++i) acc[i] = 0.f;

    const int cbeg = slice * CPS;
#pragma unroll
    for (int kd = 0; kd < 3; ++kd)
#pragma unroll
    for (int kh = 0; kh < 3; ++kh)
#pragma unroll
    for (int kw = 0; kw < 3; ++kw) {
        const int tap = (kd * 3 + kh) * 3 + kw;
        const int zd = d0 + kd - 1, zh = h0 + kh - 1, zw = w0 + kw - 1;
        const bool ok = ((unsigned)zd < (unsigned)D) & ((unsigned)zh < (unsigned)H) &
                        ((unsigned)zw < (unsigned)W);
        const int sp = (zd * H + zh) * W + zw;
        const float* wrow = &wlds[tap * CIN * COB];
        for (int c = 0; c < CPS; ++c) {
            const int ci = cbeg + c;
            const float xv = ok ? in[(size_t)ci * V + sp] : 0.f;
            const float* wp = wrow + ci * COB;
#pragma unroll
            for (int co = 0; co < COB; ++co)
                acc[co] = fmaf(xv, wp[co], acc[co]);
        }
    }

    // reduce the NS slices
#pragma unroll
    for (int co = 0; co < COB; ++co)
        redbuf[(slice * COB + co) * 64 + lane] = acc[co];
    __syncthreads();
    for (int k = threadIdx.x; k < COB * 64; k += 64 * NS) {
        const int co = k >> 6;
        const int ln = k & 63;
        float s = 0.f;
#pragma unroll
        for (int sl = 0; sl < NS; ++sl)
            s += redbuf[(sl * COB + co) * 64 + ln];
        out[(size_t)(co0 + co) * V + blockIdx.x * 64 + ln] = s;
    }
}

// ---------------------------------------------------------------------------
// upconv (NN-upsample x2 + circular 2x2x2 true convolution), R2-proven shape
// ---------------------------------------------------------------------------
template <int CIN, int COB, int VOXB>
__global__ __launch_bounds__(256) void upconv_v3(const float* __restrict__ in,
                                                 const float* __restrict__ wt,
                                                 float* __restrict__ out,
                                                 int Di, int Hi, int Wi) {
    const int Do = 2 * Di, Ho = 2 * Hi, Wo = 2 * Wi;
    const int Vo = Do * Ho * Wo;
    const int Vi = Di * Hi * Wi;
    __shared__ float wlds[COB * CIN * 8];
    const int co0 = blockIdx.y * COB;
    for (int i = threadIdx.x; i < COB * CIN * 8; i += 256) {
        const int tap = i / (CIN * COB);
        const int r   = i - tap * (CIN * COB);
        const int ci  = r / COB;
        const int co  = r - ci * COB;
        wlds[i] = wt[((size_t)(co0 + co) * CIN + ci) * 8 + tap];
    }
    __syncthreads();

    const int vbase = blockIdx.x * (256 * VOXB) + threadIdx.x;
    int od[VOXB], oh[VOXB], ow[VOXB];
#pragma unroll
    for (int j = 0; j < VOXB; ++j) {
        const int v = vbase + j * 256;
        ow[j] = v % Wo;
        oh[j] = (v / Wo) % Ho;
        od[j] = v / (Wo * Ho);
    }
    float acc[COB * VOXB];
#pragma unroll
    for (int i = 0; i < COB * VOXB; ++i) acc[i] = 0.f;

#pragma unroll
    for (int kd = 0; kd < 2; ++kd)
#pragma unroll
    for (int kh = 0; kh < 2; ++kh)
#pragma unroll
    for (int kw = 0; kw < 2; ++kw) {
        const int tap = (kd * 2 + kh) * 2 + kw;
        int sp[VOXB];
#pragma unroll
        for (int j = 0; j < VOXB; ++j) {
            const int id = ((od[j] - kd + Do) & (Do - 1)) >> 1;
            const int ih = ((oh[j] - kh + Ho) & (Ho - 1)) >> 1;
            const int iw = ((ow[j] - kw + Wo) & (Wo - 1)) >> 1;
            sp[j] = (id * Hi + ih) * Wi + iw;
        }
        const float* wrow = &wlds[tap * CIN * COB];
        for (int ci = 0; ci < CIN; ++ci) {
            float xv[VOXB];
#pragma unroll
            for (int j = 0; j < VOXB; ++j)
                xv[j] = in[(size_t)ci * Vi + sp[j]];
            const float* wp = wrow + ci * COB;
#pragma unroll
            for (int co = 0; co < COB; ++co) {
                const float wgt = wp[co];
#pragma unroll
                for (int j = 0; j < VOXB; ++j)
                    acc[co * VOXB + j] = fmaf(xv[j], wgt, acc[co * VOXB + j]);
            }
        }
    }
#pragma unroll
    for (int co = 0; co < COB; ++co)
#pragma unroll
        for (int j = 0; j < VOXB; ++j)
            out[(size_t)(co0 + co) * Vo + vbase + j * 256] = acc[co * VOXB + j];
}

// ---------------------------------------------------------------------------
// upconv with block-internal ci-split (for the deep 8x8x8 -> 16^3 layer)
// ---------------------------------------------------------------------------
template <int CIN, int NS, int COB>
__global__ __launch_bounds__(64 * NS) void upconv_red(const float* __restrict__ in,
                                                      const float* __restrict__ wt,
                                                      float* __restrict__ out,
                                                      int Di, int Hi, int Wi) {
    const int Do = 2 * Di, Ho = 2 * Hi, Wo = 2 * Wi;
    const int Vo = Do * Ho * Wo;
    const int Vi = Di * Hi * Wi;
    constexpr int CPS = CIN / NS;
    __shared__ float wlds[8 * CIN * COB];
    __shared__ float redbuf[NS * COB * 64];
    const int co0   = blockIdx.y * COB;
    const int lane  = threadIdx.x & 63;
    const int slice = threadIdx.x >> 6;
    for (int i = threadIdx.x; i < 8 * CIN * COB; i += 64 * NS) {
        const int tap = i / (CIN * COB);
        const int r   = i - tap * (CIN * COB);
        const int ci  = r / COB;
        const int co  = r - ci * COB;
        wlds[i] = wt[((size_t)(co0 + co) * CIN + ci) * 8 + tap];
    }
    __syncthreads();

    const int v  = blockIdx.x * 64 + lane;
    const int ow = v % Wo;
    const int oh = (v / Wo) % Ho;
    const int od = v / (Wo * Ho);

    float acc[COB];
#pragma unroll
    for (int i = 0; i < COB; ++i) acc[i] = 0.f;

    const int cbeg = slice * CPS;
#pragma unroll
    for (int kd = 0; kd < 2; ++kd)
#pragma unroll
    for (int kh = 0; kh < 2; ++kh)
#pragma unroll
    for (int kw = 0; kw < 2; ++kw) {
        const int tap = (kd * 2 + kh) * 2 + kw;
        const int id = ((od - kd + Do) & (Do - 1)) >> 1;
        const int ih = ((oh - kh + Ho) & (Ho - 1)) >> 1;
        const int iw = ((ow - kw + Wo) & (Wo - 1)) >> 1;
        const int sp = (id * Hi + ih) * Wi + iw;
        const float* wrow = &wlds[tap * CIN * COB];
        for (int c = 0; c < CPS; ++c) {
            const int ci = cbeg + c;
            const float xv = in[(size_t)ci * Vi + sp];
            const float* wp = wrow + ci * COB;
#pragma unroll
            for (int co = 0; co < COB; ++co)
                acc[co] = fmaf(xv, wp[co], acc[co]);
        }
    }

#pragma unroll
    for (int co = 0; co < COB; ++co)
        redbuf[(slice * COB + co) * 64 + lane] = acc[co];
    __syncthreads();
    for (int k = threadIdx.x; k < COB * 64; k += 64 * NS) {
        const int co = k >> 6;
        const int ln = k & 63;
        float s = 0.f;
#pragma unroll
        for (int sl = 0; sl < NS; ++sl)
            s += redbuf[(sl * COB + co) * 64 + ln];
        out[(size_t)(co0 + co) * Vo + blockIdx.x * 64 + ln] = s;
    }
}

// ---------------------------------------------------------------------------
// BN stats: partial sums per (channel, segment), then finalize.
// ---------------------------------------------------------------------------
__global__ __launch_bounds__(256) void bn_stats_part(const float* __restrict__ x,
                                                     float* __restrict__ part,
                                                     int V, int chunk) {
    const int c = blockIdx.x, s = blockIdx.y;
    const float* p = x + (size_t)c * V + (size_t)s * chunk;
    float s1 = 0.f, s2 = 0.f;
    for (int i = threadIdx.x * 4; i < chunk; i += 256 * 4) {
        const float4 v = *(const float4*)(p + i);
        s1 += v.x + v.y + v.z + v.w;
        s2 = fmaf(v.x, v.x, s2);
        s2 = fmaf(v.y, v.y, s2);
        s2 = fmaf(v.z, v.z, s2);
        s2 = fmaf(v.w, v.w, s2);
    }
#pragma unroll
    for (int off = 32; off > 0; off >>= 1) {
        s1 += __shfl_down(s1, off, 64);
        s2 += __shfl_down(s2, off, 64);
    }
    __shared__ float sh[8];
    const int wid  = threadIdx.x >> 6;
    const int lane = threadIdx.x & 63;
    if (lane == 0) { sh[wid] = s1; sh[4 + wid] = s2; }
    __syncthreads();
    if (threadIdx.x == 0) {
        part[(c * gridDim.y + s) * 2]     = sh[0] + sh[1] + sh[2] + sh[3];
        part[(c * gridDim.y + s) * 2 + 1] = sh[4] + sh[5] + sh[6] + sh[7];
    }
}

__global__ __launch_bounds__(64) void bn_stats_final(const float* __restrict__ part,
                                                     float* __restrict__ stats,
                                                     int S, int V) {
    const int c = blockIdx.x;
    float s1 = 0.f, s2 = 0.f;
    if ((int)threadIdx.x < S) {
        s1 = part[(c * S + threadIdx.x) * 2];
        s2 = part[(c * S + threadIdx.x) * 2 + 1];
    }
#pragma unroll
    for (int off = 32; off > 0; off >>= 1) {
        s1 += __shfl_down(s1, off, 64);
        s2 += __shfl_down(s2, off, 64);
    }
    if (threadIdx.x == 0) {
        const float inv  = 1.f / (float)V;
        const float mean = s1 * inv;
        const float var  = s2 * inv - mean * mean;
        stats[2 * c]     = mean;
        stats[2 * c + 1] = rsqrtf(var + EPS);
    }
}

// ---------------------------------------------------------------------------
// BN normalize + LeakyReLU, in place, float4
// ---------------------------------------------------------------------------
__global__ __launch_bounds__(256) void bn_apply_v2(float* __restrict__ x,
                                                   const float* __restrict__ stats,
                                                   int V4, int total4) {
    const int idx = blockIdx.x * blockDim.x + threadIdx.x;
    if (idx >= total4) return;
    const int c = idx / V4;
    const float mean = stats[2 * c];
    const float rstd = stats[2 * c + 1];
    float4 v = ((float4*)x)[idx];
    float t;
    t = (v.x - mean) * rstd; v.x = t >= 0.f ? t : SLOPE * t;
    t = (v.y - mean) * rstd; v.y = t >= 0.f ? t : SLOPE * t;
    t = (v.z - mean) * rstd; v.z = t >= 0.f ? t : SLOPE * t;
    t = (v.w - mean) * rstd; v.w = t >= 0.f ? t : SLOPE * t;
    ((float4*)x)[idx] = v;
}

// ---------------------------------------------------------------------------
// 2x2x2 maxpool stride 2
// ---------------------------------------------------------------------------
__global__ __launch_bounds__(256) void maxpool_kernel(const float* __restrict__ in,
                                                      float* __restrict__ out,
                                                      int D, int H, int W, int total) {
    const int Do = D >> 1, Ho = H >> 1, Wo = W >> 1;
    const int Vo = Do * Ho * Wo;
    const int idx = blockIdx.x * blockDim.x + threadIdx.x;
    if (idx >= total) return;
    const int c  = idx / Vo;
    const int v  = idx - c * Vo;
    const int ow = v % Wo;
    const int oh = (v / Wo) % Ho;
    const int od = v / (Wo * Ho);
    const size_t HW = (size_t)H * W;
    const float* p = in + (size_t)c * D * HW + (size_t)(2 * od) * HW + (size_t)(2 * oh) * W + 2 * ow;
    float m = p[0];
    m = fmaxf(m, p[1]);
    m = fmaxf(m, p[W]);
    m = fmaxf(m, p[W + 1]);
    m = fmaxf(m, p[HW]);
    m = fmaxf(m, p[HW + 1]);
    m = fmaxf(m, p[HW + W]);
    m = fmaxf(m, p[HW + W + 1]);
    out[idx] = m;
}

// ---------------------------------------------------------------------------
// final 1x1x1 conv + bias, float4
// ---------------------------------------------------------------------------
__global__ __launch_bounds__(256) void final_v2(const float* __restrict__ in,
                                                const float* __restrict__ w,
                                                const float* __restrict__ b,
                                                float* __restrict__ out, int C, int V4) {
    const int idx = blockIdx.x * blockDim.x + threadIdx.x;
    if (idx >= V4) return;
    const float bb = b[0];
    float4 acc = make_float4(bb, bb, bb, bb);
    for (int c = 0; c < C; ++c) {
        const float4 v = ((const float4*)in)[(size_t)c * V4 + idx];
        const float wc = w[c];
        acc.x = fmaf(v.x, wc, acc.x);
        acc.y = fmaf(v.y, wc, acc.y);
        acc.z = fmaf(v.z, wc, acc.z);
        acc.w = fmaf(v.w, wc, acc.w);
    }
    ((float4*)out)[idx] = acc;
}

// ---------------------------------------------------------------------------

extern "C" void kernel_launch(void* const* d_in, const int* in_sizes, int n_in,
                              void* d_out, int out_size, void* d_ws, size_t ws_size,
                              hipStream_t stream) {
    const float* x      = (const float*)d_in[0];
    const float* wf1    = (const float*)d_in[1];
    const float* wf2    = (const float*)d_in[2];
    const float* wd1a   = (const float*)d_in[3];
    const float* wd1b   = (const float*)d_in[4];
    const float* wd2a   = (const float*)d_in[5];
    const float* wd2b   = (const float*)d_in[6];
    const float* wd3a   = (const float*)d_in[7];
    const float* wd3b   = (const float*)d_in[8];
    const float* wt1    = (const float*)d_in[9];
    const float* wu1a   = (const float*)d_in[10];
    const float* wu1b   = (const float*)d_in[11];
    const float* wt2    = (const float*)d_in[12];
    const float* wu2a   = (const float*)d_in[13];
    const float* wu2b   = (const float*)d_in[14];
    const float* wt3    = (const float*)d_in[15];
    const float* wu3a   = (const float*)d_in[16];
    const float* wu3b   = (const float*)d_in[17];
    const float* w_fin  = (const float*)d_in[18];
    const float* b_fin  = (const float*)d_in[19];
    float* out = (float*)d_out;

    const int V0 = 64 * 64 * 64;
    const int V1 = 32 * 32 * 32;
    const int V2 = 16 * 16 * 16;
    const int V3 = 8 * 8 * 8;

    float* ws    = (float*)d_ws;
    float* cat3  = ws;                         // 32 * V0   (x1 | up3)
    float* cat2  = cat3 + (size_t)32 * V0;     // 64 * V1   (x2 | up2)
    float* cat1  = cat2 + (size_t)64 * V1;     // 128 * V2  (x3 | up1)
    float* x4    = cat1 + (size_t)128 * V2;    // 128 * V3
    float* tA    = x4   + (size_t)128 * V3;    // 16 * V0
    float* tB    = tA   + (size_t)16 * V0;     // 16 * V0
    float* stats = tB   + (size_t)16 * V0;     // 256
    float* pstat = stats + 256;                // 128*16*2

    auto blocks = [](int n) { return (n + 255) / 256; };

    auto bn_lrelu = [&](float* o, int C, int V) {
        const int NSEG = (V >= V0) ? 16 : (V == V1) ? 8 : (V == V2) ? 2 : 1;
        hipLaunchKernelGGL(bn_stats_part, dim3(C, NSEG), dim3(256), 0, stream, o, pstat, V, V / NSEG);
        hipLaunchKernelGGL(bn_stats_final, dim3(C), dim3(64), 0, stream, pstat, stats, NSEG, V);
        const int total4 = C * V / 4;
        hipLaunchKernelGGL(bn_apply_v2, dim3(blocks(total4)), dim3(256), 0, stream, o, stats, V / 4, total4);
    };
    auto maxpool = [&](const float* in, float* o, int C, int D, int H, int W) {
        const int total = C * (D / 2) * (H / 2) * (W / 2);
        hipLaunchKernelGGL(maxpool_kernel, dim3(blocks(total)), dim3(256), 0, stream,
                           in, o, D, H, W, total);
    };

    // v3 conv: grid (V/(256*VOXB), Cout/COB)
#define CONV(CIN, COB, VOXB, in_, wt_, out_, Cout, D_, H_, W_)                              \
    {                                                                                       \
        const int V_ = (D_) * (H_) * (W_);                                                  \
        dim3 g(V_ / (256 * (VOXB)), (Cout) / (COB));                                        \
        hipLaunchKernelGGL((conv3_v3<CIN, COB, VOXB>), g, dim3(256), 0, stream,             \
                           in_, wt_, out_, D_, H_, W_);                                     \
        bn_lrelu(out_, Cout, V_);                                                           \
    }
    // ci-split conv: grid (V/64, Cout/COB), block 64*NS
#define CONVR(CIN, NS, COB, in_, wt_, out_, Cout, D_, H_, W_)                               \
    {                                                                                       \
        const int V_ = (D_) * (H_) * (W_);                                                  \
        dim3 g(V_ / 64, (Cout) / (COB));                                                    \
        hipLaunchKernelGGL((conv3_red<CIN, NS, COB>), g, dim3(64 * (NS)), 0, stream,        \
                           in_, wt_, out_, D_, H_, W_);                                     \
        bn_lrelu(out_, Cout, V_);                                                           \
    }
#define UPCONV(CIN, COB, VOXB, in_, wt_, out_, Cout, Di_, Hi_, Wi_)                         \
    {                                                                                       \
        const int Vo_ = 8 * (Di_) * (Hi_) * (Wi_);                                          \
        dim3 g(Vo_ / (256 * (VOXB)), (Cout) / (COB));                                       \
        hipLaunchKernelGGL((upconv_v3<CIN, COB, VOXB>), g, dim3(256), 0, stream,            \
                           in_, wt_, out_, Di_, Hi_, Wi_);                                  \
        bn_lrelu(out_, Cout, Vo_);                                                          \
    }
#define UPCONVR(CIN, NS, COB, in_, wt_, out_, Cout, Di_, Hi_, Wi_)                          \
    {                                                                                       \
        const int Vo_ = 8 * (Di_) * (Hi_) * (Wi_);                                          \
        dim3 g(Vo_ / 64, (Cout) / (COB));                                                   \
        hipLaunchKernelGGL((upconv_red<CIN, NS, COB>), g, dim3(64 * (NS)), 0, stream,       \
                           in_, wt_, out_, Di_, Hi_, Wi_);                                  \
        bn_lrelu(out_, Cout, Vo_);                                                          \
    }

    // ----- encoder -----                                      blocks
    CONV(1,  8, 2, x,   wf1,  tA,   16, 64, 64, 64);            // (512,2)=1024
    CONV(16, 8, 2, tA,  wf2,  cat3, 16, 64, 64, 64);            // 1024
    maxpool(cat3, tA, 16, 64, 64, 64);
    CONV(16, 8, 1, tA,  wd1a, tB,   32, 32, 32, 32);            // (128,4)=512
    CONV(32, 8, 1, tB,  wd1b, cat2, 32, 32, 32, 32);            // 512
    maxpool(cat2, tA, 32, 32, 32, 32);
    CONVR(32, 4, 4, tA, wd2a, tB,   64, 16, 16, 16);            // (64,16)=1024
    CONVR(64, 4, 4, tB, wd2b, cat1, 64, 16, 16, 16);            // 1024
    maxpool(cat1, tA, 64, 16, 16, 16);
    CONVR(64,  4, 2, tA, wd3a, tB,  128, 8, 8, 8);              // (8,64)=512
    CONVR(128, 4, 2, tB, wd3b, x4,  128, 8, 8, 8);              // 512

    // ----- decoder -----
    UPCONVR(128, 4, 4, x4, wt1, cat1 + (size_t)64 * V2, 64, 8, 8, 8);   // (64,16)=1024
    CONVR(128, 4, 4, cat1, wu1a, tA, 64, 16, 16, 16);           // 1024
    CONVR(64,  4, 4, tA,   wu1b, tB, 64, 16, 16, 16);           // 1024

    UPCONV(64, 8, 1, tB, wt2, cat2 + (size_t)32 * V1, 32, 16, 16, 16);  // (128,4)=512
    CONV(64, 8, 1, cat2, wu2a, tA, 32, 32, 32, 32);             // 512
    CONV(32, 8, 1, tA,   wu2b, tB, 32, 32, 32, 32);             // 512

    UPCONV(32, 8, 2, tB, wt3, cat3 + (size_t)16 * V0, 16, 32, 32, 32);  // (512,2)=1024
    CONV(32, 8, 2, cat3, wu3a, tA, 16, 64, 64, 64);             // 1024
    CONV(16, 8, 2, tA,   wu3b, tB, 16, 64, 64, 64);             // 1024

    // ----- final 1x1x1 conv + bias -----
    hipLaunchKernelGGL(final_v2, dim3(blocks(V0 / 4)), dim3(256), 0, stream,
                       tB, w_fin, b_fin, out, 16, V0 / 4);

#undef CONV
#undef CONVR
#undef UPCONV
#undef UPCONVR
}

// Round 6
// 1891.090 us; speedup vs baseline: 12.3243x; 12.3243x over previous
//
#include <hip/hip_runtime.h>

#define EPS   1e-5f
#define SLOPE 0.01f

// ---------------------------------------------------------------------------
// conv 3x3x3 pad=1 (cross-correlation), cout-register-blocked.
// in: [CIN][D][H][W], wt: [Cout][CIN][3][3][3]
// ci loop pinned to unroll 4: bounds in-flight loads to 4*VOXB, keeps VGPR<128
// for ALL instantiations (R4/R5 lesson: heuristic unroll -> 256 VGPR + spills).
// ---------------------------------------------------------------------------
template <int CIN, int COB, int VOXB>
__global__ __launch_bounds__(256) void conv3_v6(const float* __restrict__ in,
                                                const float* __restrict__ wt,
                                                float* __restrict__ out,
                                                int D, int H, int W) {
    const int V = D * H * W;
    __shared__ float wlds[COB * CIN * 27];
    const int co0 = blockIdx.y * COB;
    for (int i = threadIdx.x; i < COB * CIN * 27; i += 256) {
        const int tap = i / (CIN * COB);
        const int r   = i - tap * (CIN * COB);
        const int ci  = r / COB;
        const int co  = r - ci * COB;
        wlds[i] = wt[((size_t)(co0 + co) * CIN + ci) * 27 + tap];
    }
    __syncthreads();

    const int vbase = blockIdx.x * (256 * VOXB) + threadIdx.x;
    int dd[VOXB], hh[VOXB], ww[VOXB];
#pragma unroll
    for (int j = 0; j < VOXB; ++j) {
        const int v = vbase + j * 256;
        ww[j] = v % W;
        hh[j] = (v / W) % H;
        dd[j] = v / (W * H);
    }
    float acc[COB * VOXB];
#pragma unroll
    for (int i = 0; i < COB * VOXB; ++i) acc[i] = 0.f;

#pragma unroll 1
    for (int kd = 0; kd < 3; ++kd)
#pragma unroll 1
    for (int kh = 0; kh < 3; ++kh)
#pragma unroll
    for (int kw = 0; kw < 3; ++kw) {
        const int tap = (kd * 3 + kh) * 3 + kw;
        int sp[VOXB]; bool ok[VOXB];
#pragma unroll
        for (int j = 0; j < VOXB; ++j) {
            const int zd = dd[j] + kd - 1, zh = hh[j] + kh - 1, zw = ww[j] + kw - 1;
            ok[j] = ((unsigned)zd < (unsigned)D) & ((unsigned)zh < (unsigned)H) &
                    ((unsigned)zw < (unsigned)W);
            sp[j] = (zd * H + zh) * W + zw;
        }
        const float* wrow = &wlds[tap * CIN * COB];
#pragma unroll 4
        for (int ci = 0; ci < CIN; ++ci) {
            float xv[VOXB];
#pragma unroll
            for (int j = 0; j < VOXB; ++j)
                xv[j] = ok[j] ? in[(size_t)ci * V + sp[j]] : 0.f;
            const float* wp = wrow + ci * COB;
#pragma unroll
            for (int co = 0; co < COB; ++co) {
                const float wgt = wp[co];
#pragma unroll
                for (int j = 0; j < VOXB; ++j)
                    acc[co * VOXB + j] = fmaf(xv[j], wgt, acc[co * VOXB + j]);
            }
        }
    }
#pragma unroll
    for (int co = 0; co < COB; ++co)
#pragma unroll
        for (int j = 0; j < VOXB; ++j)
            out[(size_t)(co0 + co) * V + vbase + j * 256] = acc[co * VOXB + j];
}

// ---------------------------------------------------------------------------
// upconv (NN-upsample x2 + circular 2x2x2 true convolution), same discipline
// ---------------------------------------------------------------------------
template <int CIN, int COB, int VOXB>
__global__ __launch_bounds__(256) void upconv_v6(const float* __restrict__ in,
                                                 const float* __restrict__ wt,
                                                 float* __restrict__ out,
                                                 int Di, int Hi, int Wi) {
    const int Do = 2 * Di, Ho = 2 * Hi, Wo = 2 * Wi;
    const int Vo = Do * Ho * Wo;
    const int Vi = Di * Hi * Wi;
    __shared__ float wlds[COB * CIN * 8];
    const int co0 = blockIdx.y * COB;
    for (int i = threadIdx.x; i < COB * CIN * 8; i += 256) {
        const int tap = i / (CIN * COB);
        const int r   = i - tap * (CIN * COB);
        const int ci  = r / COB;
        const int co  = r - ci * COB;
        wlds[i] = wt[((size_t)(co0 + co) * CIN + ci) * 8 + tap];
    }
    __syncthreads();

    const int vbase = blockIdx.x * (256 * VOXB) + threadIdx.x;
    int od[VOXB], oh[VOXB], ow[VOXB];
#pragma unroll
    for (int j = 0; j < VOXB; ++j) {
        const int v = vbase + j * 256;
        ow[j] = v % Wo;
        oh[j] = (v / Wo) % Ho;
        od[j] = v / (Wo * Ho);
    }
    float acc[COB * VOXB];
#pragma unroll
    for (int i = 0; i < COB * VOXB; ++i) acc[i] = 0.f;

#pragma unroll 1
    for (int kd = 0; kd < 2; ++kd)
#pragma unroll 1
    for (int kh = 0; kh < 2; ++kh)
#pragma unroll
    for (int kw = 0; kw < 2; ++kw) {
        const int tap = (kd * 2 + kh) * 2 + kw;
        int sp[VOXB];
#pragma unroll
        for (int j = 0; j < VOXB; ++j) {
            const int id = ((od[j] - kd + Do) & (Do - 1)) >> 1;
            const int ih = ((oh[j] - kh + Ho) & (Ho - 1)) >> 1;
            const int iw = ((ow[j] - kw + Wo) & (Wo - 1)) >> 1;
            sp[j] = (id * Hi + ih) * Wi + iw;
        }
        const float* wrow = &wlds[tap * CIN * COB];
#pragma unroll 4
        for (int ci = 0; ci < CIN; ++ci) {
            float xv[VOXB];
#pragma unroll
            for (int j = 0; j < VOXB; ++j)
                xv[j] = in[(size_t)ci * Vi + sp[j]];
            const float* wp = wrow + ci * COB;
#pragma unroll
            for (int co = 0; co < COB; ++co) {
                const float wgt = wp[co];
#pragma unroll
                for (int j = 0; j < VOXB; ++j)
                    acc[co * VOXB + j] = fmaf(xv[j], wgt, acc[co * VOXB + j]);
            }
        }
    }
#pragma unroll
    for (int co = 0; co < COB; ++co)
#pragma unroll
        for (int j = 0; j < VOXB; ++j)
            out[(size_t)(co0 + co) * Vo + vbase + j * 256] = acc[co * VOXB + j];
}

// ---------------------------------------------------------------------------
// BN stats: partial sums per (channel, segment), then finalize.
// ---------------------------------------------------------------------------
__global__ __launch_bounds__(256) void bn_stats_part(const float* __restrict__ x,
                                                     float* __restrict__ part,
                                                     int V, int chunk) {
    const int c = blockIdx.x, s = blockIdx.y;
    const float* p = x + (size_t)c * V + (size_t)s * chunk;
    float s1 = 0.f, s2 = 0.f;
    for (int i = threadIdx.x * 4; i < chunk; i += 256 * 4) {
        const float4 v = *(const float4*)(p + i);
        s1 += v.x + v.y + v.z + v.w;
        s2 = fmaf(v.x, v.x, s2);
        s2 = fmaf(v.y, v.y, s2);
        s2 = fmaf(v.z, v.z, s2);
        s2 = fmaf(v.w, v.w, s2);
    }
#pragma unroll
    for (int off = 32; off > 0; off >>= 1) {
        s1 += __shfl_down(s1, off, 64);
        s2 += __shfl_down(s2, off, 64);
    }
    __shared__ float sh[8];
    const int wid  = threadIdx.x >> 6;
    const int lane = threadIdx.x & 63;
    if (lane == 0) { sh[wid] = s1; sh[4 + wid] = s2; }
    __syncthreads();
    if (threadIdx.x == 0) {
        part[(c * gridDim.y + s) * 2]     = sh[0] + sh[1] + sh[2] + sh[3];
        part[(c * gridDim.y + s) * 2 + 1] = sh[4] + sh[5] + sh[6] + sh[7];
    }
}

__global__ __launch_bounds__(64) void bn_stats_final(const float* __restrict__ part,
                                                     float* __restrict__ stats,
                                                     int S, int V) {
    const int c = blockIdx.x;
    float s1 = 0.f, s2 = 0.f;
    if ((int)threadIdx.x < S) {
        s1 = part[(c * S + threadIdx.x) * 2];
        s2 = part[(c * S + threadIdx.x) * 2 + 1];
    }
#pragma unroll
    for (int off = 32; off > 0; off >>= 1) {
        s1 += __shfl_down(s1, off, 64);
        s2 += __shfl_down(s2, off, 64);
    }
    if (threadIdx.x == 0) {
        const float inv  = 1.f / (float)V;
        const float mean = s1 * inv;
        const float var  = s2 * inv - mean * mean;
        stats[2 * c]     = mean;
        stats[2 * c + 1] = rsqrtf(var + EPS);
    }
}

// ---------------------------------------------------------------------------
// BN normalize + LeakyReLU, in place, float4
// ---------------------------------------------------------------------------
__global__ __launch_bounds__(256) void bn_apply_v2(float* __restrict__ x,
                                                   const float* __restrict__ stats,
                                                   int V4, int total4) {
    const int idx = blockIdx.x * blockDim.x + threadIdx.x;
    if (idx >= total4) return;
    const int c = idx / V4;
    const float mean = stats[2 * c];
    const float rstd = stats[2 * c + 1];
    float4 v = ((float4*)x)[idx];
    float t;
    t = (v.x - mean) * rstd; v.x = t >= 0.f ? t : SLOPE * t;
    t = (v.y - mean) * rstd; v.y = t >= 0.f ? t : SLOPE * t;
    t = (v.z - mean) * rstd; v.z = t >= 0.f ? t : SLOPE * t;
    t = (v.w - mean) * rstd; v.w = t >= 0.f ? t : SLOPE * t;
    ((float4*)x)[idx] = v;
}

// ---------------------------------------------------------------------------
// 2x2x2 maxpool stride 2
// ---------------------------------------------------------------------------
__global__ __launch_bounds__(256) void maxpool_kernel(const float* __restrict__ in,
                                                      float* __restrict__ out,
                                                      int D, int H, int W, int total) {
    const int Do = D >> 1, Ho = H >> 1, Wo = W >> 1;
    const int Vo = Do * Ho * Wo;
    const int idx = blockIdx.x * blockDim.x + threadIdx.x;
    if (idx >= total) return;
    const int c  = idx / Vo;
    const int v  = idx - c * Vo;
    const int ow = v % Wo;
    const int oh = (v / Wo) % Ho;
    const int od = v / (Wo * Ho);
    const size_t HW = (size_t)H * W;
    const float* p = in + (size_t)c * D * HW + (size_t)(2 * od) * HW + (size_t)(2 * oh) * W + 2 * ow;
    float m = p[0];
    m = fmaxf(m, p[1]);
    m = fmaxf(m, p[W]);
    m = fmaxf(m, p[W + 1]);
    m = fmaxf(m, p[HW]);
    m = fmaxf(m, p[HW + 1]);
    m = fmaxf(m, p[HW + W]);
    m = fmaxf(m, p[HW + W + 1]);
    out[idx] = m;
}

// ---------------------------------------------------------------------------
// final 1x1x1 conv + bias, float4
// ---------------------------------------------------------------------------
__global__ __launch_bounds__(256) void final_v2(const float* __restrict__ in,
                                                const float* __restrict__ w,
                                                const float* __restrict__ b,
                                                float* __restrict__ out, int C, int V4) {
    const int idx = blockIdx.x * blockDim.x + threadIdx.x;
    if (idx >= V4) return;
    const float bb = b[0];
    float4 acc = make_float4(bb, bb, bb, bb);
    for (int c = 0; c < C; ++c) {
        const float4 v = ((const float4*)in)[(size_t)c * V4 + idx];
        const float wc = w[c];
        acc.x = fmaf(v.x, wc, acc.x);
        acc.y = fmaf(v.y, wc, acc.y);
        acc.z = fmaf(v.z, wc, acc.z);
        acc.w = fmaf(v.w, wc, acc.w);
    }
    ((float4*)out)[idx] = acc;
}

// ---------------------------------------------------------------------------

extern "C" void kernel_launch(void* const* d_in, const int* in_sizes, int n_in,
                              void* d_out, int out_size, void* d_ws, size_t ws_size,
                              hipStream_t stream) {
    const float* x      = (const float*)d_in[0];
    const float* wf1    = (const float*)d_in[1];
    const float* wf2    = (const float*)d_in[2];
    const float* wd1a   = (const float*)d_in[3];
    const float* wd1b   = (const float*)d_in[4];
    const float* wd2a   = (const float*)d_in[5];
    const float* wd2b   = (const float*)d_in[6];
    const float* wd3a   = (const float*)d_in[7];
    const float* wd3b   = (const float*)d_in[8];
    const float* wt1    = (const float*)d_in[9];
    const float* wu1a   = (const float*)d_in[10];
    const float* wu1b   = (const float*)d_in[11];
    const float* wt2    = (const float*)d_in[12];
    const float* wu2a   = (const float*)d_in[13];
    const float* wu2b   = (const float*)d_in[14];
    const float* wt3    = (const float*)d_in[15];
    const float* wu3a   = (const float*)d_in[16];
    const float* wu3b   = (const float*)d_in[17];
    const float* w_fin  = (const float*)d_in[18];
    const float* b_fin  = (const float*)d_in[19];
    float* out = (float*)d_out;

    const int V0 = 64 * 64 * 64;
    const int V1 = 32 * 32 * 32;
    const int V2 = 16 * 16 * 16;
    const int V3 = 8 * 8 * 8;

    float* ws    = (float*)d_ws;
    float* cat3  = ws;                         // 32 * V0   (x1 | up3)
    float* cat2  = cat3 + (size_t)32 * V0;     // 64 * V1   (x2 | up2)
    float* cat1  = cat2 + (size_t)64 * V1;     // 128 * V2  (x3 | up1)
    float* x4    = cat1 + (size_t)128 * V2;    // 128 * V3
    float* tA    = x4   + (size_t)128 * V3;    // 16 * V0
    float* tB    = tA   + (size_t)16 * V0;     // 16 * V0
    float* stats = tB   + (size_t)16 * V0;     // 256
    float* pstat = stats + 256;                // 128*16*2

    auto blocks = [](int n) { return (n + 255) / 256; };

    auto bn_lrelu = [&](float* o, int C, int V) {
        const int NSEG = (V >= V0) ? 16 : (V == V1) ? 8 : (V == V2) ? 2 : 1;
        hipLaunchKernelGGL(bn_stats_part, dim3(C, NSEG), dim3(256), 0, stream, o, pstat, V, V / NSEG);
        hipLaunchKernelGGL(bn_stats_final, dim3(C), dim3(64), 0, stream, pstat, stats, NSEG, V);
        const int total4 = C * V / 4;
        hipLaunchKernelGGL(bn_apply_v2, dim3(blocks(total4)), dim3(256), 0, stream, o, stats, V / 4, total4);
    };
    auto maxpool = [&](const float* in, float* o, int C, int D, int H, int W) {
        const int total = C * (D / 2) * (H / 2) * (W / 2);
        hipLaunchKernelGGL(maxpool_kernel, dim3(blocks(total)), dim3(256), 0, stream,
                           in, o, D, H, W, total);
    };

#define CONV(CIN, COB, VOXB, in_, wt_, out_, Cout, D_, H_, W_)                              \
    {                                                                                       \
        const int V_ = (D_) * (H_) * (W_);                                                  \
        dim3 g(V_ / (256 * (VOXB)), (Cout) / (COB));                                        \
        hipLaunchKernelGGL((conv3_v6<CIN, COB, VOXB>), g, dim3(256), 0, stream,             \
                           in_, wt_, out_, D_, H_, W_);                                     \
        bn_lrelu(out_, Cout, V_);                                                           \
    }
#define UPCONV(CIN, COB, VOXB, in_, wt_, out_, Cout, Di_, Hi_, Wi_)                         \
    {                                                                                       \
        const int Vo_ = 8 * (Di_) * (Hi_) * (Wi_);                                          \
        dim3 g(Vo_ / (256 * (VOXB)), (Cout) / (COB));                                       \
        hipLaunchKernelGGL((upconv_v6<CIN, COB, VOXB>), g, dim3(256), 0, stream,            \
                           in_, wt_, out_, Di_, Hi_, Wi_);                                  \
        bn_lrelu(out_, Cout, Vo_);                                                          \
    }

    // ----- encoder -----                                      blocks
    CONV(1,  8, 4, x,   wf1,  tA,   16, 64, 64, 64);            // (256,2)=512
    CONV(16, 8, 4, tA,  wf2,  cat3, 16, 64, 64, 64);            // 512
    maxpool(cat3, tA, 16, 64, 64, 64);
    CONV(16, 8, 1, tA,  wd1a, tB,   32, 32, 32, 32);            // (128,4)=512
    CONV(32, 8, 1, tB,  wd1b, cat2, 32, 32, 32, 32);            // 512
    maxpool(cat2, tA, 32, 32, 32, 32);
    CONV(32, 4, 1, tA,  wd2a, tB,   64, 16, 16, 16);            // (16,16)=256
    CONV(64, 4, 1, tB,  wd2b, cat1, 64, 16, 16, 16);            // 256
    maxpool(cat1, tA, 64, 16, 16, 16);
    CONV(64,  4, 1, tA, wd3a, tB,  128, 8, 8, 8);               // (2,32)=64
    CONV(128, 4, 1, tB, wd3b, x4,  128, 8, 8, 8);               // 64

    // ----- decoder -----
    UPCONV(128, 4, 1, x4, wt1, cat1 + (size_t)64 * V2, 64, 8, 8, 8);    // (16,16)=256
    CONV(128, 4, 1, cat1, wu1a, tA, 64, 16, 16, 16);            // 256
    CONV(64,  4, 1, tA,   wu1b, tB, 64, 16, 16, 16);            // 256

    UPCONV(64, 8, 1, tB, wt2, cat2 + (size_t)32 * V1, 32, 16, 16, 16);  // (128,4)=512
    CONV(64, 8, 1, cat2, wu2a, tA, 32, 32, 32, 32);             // 512
    CONV(32, 8, 1, tA,   wu2b, tB, 32, 32, 32, 32);             // 512

    UPCONV(32, 8, 4, tB, wt3, cat3 + (size_t)16 * V0, 16, 32, 32, 32);  // (256,2)=512
    CONV(32, 8, 4, cat3, wu3a, tA, 16, 64, 64, 64);             // 512
    CONV(16, 8, 4, tA,   wu3b, tB, 16, 64, 64, 64);             // 512

    // ----- final 1x1x1 conv + bias -----
    hipLaunchKernelGGL(final_v2, dim3(blocks(V0 / 4)), dim3(256), 0, stream,
                       tB, w_fin, b_fin, out, 16, V0 / 4);

#undef CONV
#undef UPCONV
}

// Round 7
// 1728.876 us; speedup vs baseline: 13.4806x; 1.0938x over previous
//
#include <hip/hip_runtime.h>

#define EPS   1e-5f
#define SLOPE 0.01f

// ---------------------------------------------------------------------------
// conv 3x3x3 pad=1 (cross-correlation), quad-vectorized voxels + ci-split.
// Each thread computes 4 consecutive W-voxels for COB output channels.
// Per (ci, kd, kh): ONE aligned float4 + 2 clamped edge scalars serve all 3 kw
// taps (12 FMAs/co). grid: (V/(4*BT), Cout/COB, CIN/CC); partials to part[z].
// Tap loops pinned unroll 1, ci loop unroll 4 (R4/R5 lesson: bound in-flight
// loads or the allocator explodes to 256 VGPR + scratch spills).
// ---------------------------------------------------------------------------
template <int CIN, int CC, int COB, int BT>
__global__ __launch_bounds__(BT) void conv3_q(const float* __restrict__ in,
                                              const float* __restrict__ wt,
                                              float* __restrict__ part,
                                              int D, int H, int W) {
    const int V    = D * H * W;
    const int Cout = gridDim.y * COB;
    const int z    = blockIdx.z;
    const int cib  = z * CC;
    __shared__ float wlds[27 * CC * COB];
    const int co0 = blockIdx.y * COB;
    for (int i = threadIdx.x; i < 27 * CC * COB; i += BT) {
        const int tap = i / (CC * COB);
        const int r   = i - tap * (CC * COB);
        const int ci  = r / COB;
        const int co  = r - ci * COB;
        wlds[i] = wt[((size_t)(co0 + co) * CIN + cib + ci) * 27 + tap];
    }
    __syncthreads();

    const float* inz = in + (size_t)cib * V;
    const int v0 = (blockIdx.x * BT + threadIdx.x) * 4;   // first voxel of quad
    const int w0 = v0 % W;
    const int h0 = (v0 / W) % H;
    const int d0 = v0 / (W * H);

    const bool mL = (w0 != 0);
    const bool mR = (w0 + 4 != W);
    const int  wl = w0 - (mL ? 1 : 0);    // clamped: always in-row
    const int  wr = w0 + (mR ? 4 : 3);

    float acc[COB * 4];
#pragma unroll
    for (int i = 0; i < COB * 4; ++i) acc[i] = 0.f;

#pragma unroll 1
    for (int kd = 0; kd < 3; ++kd) {
#pragma unroll 1
        for (int kh = 0; kh < 3; ++kh) {
            const int zd = d0 + kd - 1, zh = h0 + kh - 1;
            const bool okp = ((unsigned)zd < (unsigned)D) & ((unsigned)zh < (unsigned)H);
            const int row = okp ? (zd * H + zh) * W : 0;   // clamped: never faults
            const float* wp0 = &wlds[((kd * 3 + kh) * 3 + 0) * CC * COB];
            const float* wp1 = wp0 + CC * COB;
            const float* wp2 = wp1 + CC * COB;
#pragma unroll 4
            for (int ci = 0; ci < CC; ++ci) {
                const float* p = inz + (size_t)ci * V + row;
                float4 m = *(const float4*)(p + w0);
                float lv = p[wl];
                float rv = p[wr];
                if (!okp) { m.x = 0.f; m.y = 0.f; m.z = 0.f; m.w = 0.f; }
                if (!(okp && mL)) lv = 0.f;
                if (!(okp && mR)) rv = 0.f;
#pragma unroll
                for (int co = 0; co < COB; ++co) {
                    const float a0 = wp0[ci * COB + co];
                    const float a1 = wp1[ci * COB + co];
                    const float a2 = wp2[ci * COB + co];
                    float* a = &acc[co * 4];
                    a[0] = fmaf(lv,  a0, fmaf(m.x, a1, fmaf(m.y, a2, a[0])));
                    a[1] = fmaf(m.x, a0, fmaf(m.y, a1, fmaf(m.z, a2, a[1])));
                    a[2] = fmaf(m.y, a0, fmaf(m.z, a1, fmaf(m.w, a2, a[2])));
                    a[3] = fmaf(m.z, a0, fmaf(m.w, a1, fmaf(rv,  a2, a[3])));
                }
            }
        }
    }
#pragma unroll
    for (int co = 0; co < COB; ++co)
        *(float4*)&part[((size_t)z * Cout + co0 + co) * V + v0] = *(const float4*)&acc[co * 4];
}

// ---------------------------------------------------------------------------
// upconv (NN-upsample x2 + circular 2x2x2 true convolution), R6-proven shape
// ---------------------------------------------------------------------------
template <int CIN, int COB, int VOXB>
__global__ __launch_bounds__(256) void upconv_v6(const float* __restrict__ in,
                                                 const float* __restrict__ wt,
                                                 float* __restrict__ out,
                                                 int Di, int Hi, int Wi) {
    const int Do = 2 * Di, Ho = 2 * Hi, Wo = 2 * Wi;
    const int Vo = Do * Ho * Wo;
    const int Vi = Di * Hi * Wi;
    __shared__ float wlds[COB * CIN * 8];
    const int co0 = blockIdx.y * COB;
    for (int i = threadIdx.x; i < COB * CIN * 8; i += 256) {
        const int tap = i / (CIN * COB);
        const int r   = i - tap * (CIN * COB);
        const int ci  = r / COB;
        const int co  = r - ci * COB;
        wlds[i] = wt[((size_t)(co0 + co) * CIN + ci) * 8 + tap];
    }
    __syncthreads();

    const int vbase = blockIdx.x * (256 * VOXB) + threadIdx.x;
    int od[VOXB], oh[VOXB], ow[VOXB];
#pragma unroll
    for (int j = 0; j < VOXB; ++j) {
        const int v = vbase + j * 256;
        ow[j] = v % Wo;
        oh[j] = (v / Wo) % Ho;
        od[j] = v / (Wo * Ho);
    }
    float acc[COB * VOXB];
#pragma unroll
    for (int i = 0; i < COB * VOXB; ++i) acc[i] = 0.f;

#pragma unroll 1
    for (int kd = 0; kd < 2; ++kd)
#pragma unroll 1
    for (int kh = 0; kh < 2; ++kh)
#pragma unroll
    for (int kw = 0; kw < 2; ++kw) {
        const int tap = (kd * 2 + kh) * 2 + kw;
        int sp[VOXB];
#pragma unroll
        for (int j = 0; j < VOXB; ++j) {
            const int id = ((od[j] - kd + Do) & (Do - 1)) >> 1;
            const int ih = ((oh[j] - kh + Ho) & (Ho - 1)) >> 1;
            const int iw = ((ow[j] - kw + Wo) & (Wo - 1)) >> 1;
            sp[j] = (id * Hi + ih) * Wi + iw;
        }
        const float* wrow = &wlds[tap * CIN * COB];
#pragma unroll 4
        for (int ci = 0; ci < CIN; ++ci) {
            float xv[VOXB];
#pragma unroll
            for (int j = 0; j < VOXB; ++j)
                xv[j] = in[(size_t)ci * Vi + sp[j]];
            const float* wp = wrow + ci * COB;
#pragma unroll
            for (int co = 0; co < COB; ++co) {
                const float wgt = wp[co];
#pragma unroll
                for (int j = 0; j < VOXB; ++j)
                    acc[co * VOXB + j] = fmaf(xv[j], wgt, acc[co * VOXB + j]);
            }
        }
    }
#pragma unroll
    for (int co = 0; co < COB; ++co)
#pragma unroll
        for (int j = 0; j < VOXB; ++j)
            out[(size_t)(co0 + co) * Vo + vbase + j * 256] = acc[co * VOXB + j];
}

// ---------------------------------------------------------------------------
// BN stats over split partials: pstat[c][seg] = (sum, sumsq) of sum_s part[s][c][.]
// ---------------------------------------------------------------------------
__global__ __launch_bounds__(256) void bn_stats_part_v2(const float* __restrict__ part,
                                                        float* __restrict__ pstat,
                                                        int C, int V, int S, int chunk) {
    const int c = blockIdx.x, seg = blockIdx.y;
    const size_t base = (size_t)c * V + (size_t)seg * chunk;
    float s1 = 0.f, s2 = 0.f;
    for (int i = threadIdx.x * 4; i < chunk; i += 1024) {
        float4 t = make_float4(0.f, 0.f, 0.f, 0.f);
        for (int s = 0; s < S; ++s) {
            const float4 v = *(const float4*)(part + (size_t)s * C * V + base + i);
            t.x += v.x; t.y += v.y; t.z += v.z; t.w += v.w;
        }
        s1 += t.x + t.y + t.z + t.w;
        s2 = fmaf(t.x, t.x, fmaf(t.y, t.y, fmaf(t.z, t.z, fmaf(t.w, t.w, s2))));
    }
#pragma unroll
    for (int off = 32; off > 0; off >>= 1) {
        s1 += __shfl_down(s1, off, 64);
        s2 += __shfl_down(s2, off, 64);
    }
    __shared__ float sh[8];
    const int wid  = threadIdx.x >> 6;
    const int lane = threadIdx.x & 63;
    if (lane == 0) { sh[wid] = s1; sh[4 + wid] = s2; }
    __syncthreads();
    if (threadIdx.x == 0) {
        pstat[(c * gridDim.y + seg) * 2]     = sh[0] + sh[1] + sh[2] + sh[3];
        pstat[(c * gridDim.y + seg) * 2 + 1] = sh[4] + sh[5] + sh[6] + sh[7];
    }
}

__global__ __launch_bounds__(64) void bn_stats_final(const float* __restrict__ pstat,
                                                     float* __restrict__ stats,
                                                     int S, int V) {
    const int c = blockIdx.x;
    float s1 = 0.f, s2 = 0.f;
    if ((int)threadIdx.x < S) {
        s1 = pstat[(c * S + threadIdx.x) * 2];
        s2 = pstat[(c * S + threadIdx.x) * 2 + 1];
    }
#pragma unroll
    for (int off = 32; off > 0; off >>= 1) {
        s1 += __shfl_down(s1, off, 64);
        s2 += __shfl_down(s2, off, 64);
    }
    if (threadIdx.x == 0) {
        const float inv  = 1.f / (float)V;
        const float mean = s1 * inv;
        const float var  = s2 * inv - mean * mean;
        stats[2 * c]     = mean;
        stats[2 * c + 1] = rsqrtf(var + EPS);
    }
}

// ---------------------------------------------------------------------------
// split-reduce + BN normalize + LeakyReLU: dst = lrelu((sum_s part[s] - m) * rstd)
// ---------------------------------------------------------------------------
__global__ __launch_bounds__(256) void bn_apply_v3(const float* __restrict__ part,
                                                   float* __restrict__ dst,
                                                   const float* __restrict__ stats,
                                                   int C, int V4, int S, int total4) {
    const int idx = blockIdx.x * blockDim.x + threadIdx.x;
    if (idx >= total4) return;
    const int c = idx / V4;
    const int v = idx - c * V4;
    const float4* p4 = (const float4*)part;
    float4 t = make_float4(0.f, 0.f, 0.f, 0.f);
    for (int s = 0; s < S; ++s) {
        const float4 x = p4[(size_t)(s * C + c) * V4 + v];
        t.x += x.x; t.y += x.y; t.z += x.z; t.w += x.w;
    }
    const float mean = stats[2 * c];
    const float rstd = stats[2 * c + 1];
    float u;
    u = (t.x - mean) * rstd; t.x = u >= 0.f ? u : SLOPE * u;
    u = (t.y - mean) * rstd; t.y = u >= 0.f ? u : SLOPE * u;
    u = (t.z - mean) * rstd; t.z = u >= 0.f ? u : SLOPE * u;
    u = (t.w - mean) * rstd; t.w = u >= 0.f ? u : SLOPE * u;
    ((float4*)dst)[idx] = t;
}

// ---------------------------------------------------------------------------
// 2x2x2 maxpool stride 2
// ---------------------------------------------------------------------------
__global__ __launch_bounds__(256) void maxpool_kernel(const float* __restrict__ in,
                                                      float* __restrict__ out,
                                                      int D, int H, int W, int total) {
    const int Do = D >> 1, Ho = H >> 1, Wo = W >> 1;
    const int Vo = Do * Ho * Wo;
    const int idx = blockIdx.x * blockDim.x + threadIdx.x;
    if (idx >= total) return;
    const int c  = idx / Vo;
    const int v  = idx - c * Vo;
    const int ow = v % Wo;
    const int oh = (v / Wo) % Ho;
    const int od = v / (Wo * Ho);
    const size_t HW = (size_t)H * W;
    const float* p = in + (size_t)c * D * HW + (size_t)(2 * od) * HW + (size_t)(2 * oh) * W + 2 * ow;
    float m = p[0];
    m = fmaxf(m, p[1]);
    m = fmaxf(m, p[W]);
    m = fmaxf(m, p[W + 1]);
    m = fmaxf(m, p[HW]);
    m = fmaxf(m, p[HW + 1]);
    m = fmaxf(m, p[HW + W]);
    m = fmaxf(m, p[HW + W + 1]);
    out[idx] = m;
}

// ---------------------------------------------------------------------------
// final 1x1x1 conv + bias, float4
// ---------------------------------------------------------------------------
__global__ __launch_bounds__(256) void final_v2(const float* __restrict__ in,
                                                const float* __restrict__ w,
                                                const float* __restrict__ b,
                                                float* __restrict__ out, int C, int V4) {
    const int idx = blockIdx.x * blockDim.x + threadIdx.x;
    if (idx >= V4) return;
    const float bb = b[0];
    float4 acc = make_float4(bb, bb, bb, bb);
    for (int c = 0; c < C; ++c) {
        const float4 v = ((const float4*)in)[(size_t)c * V4 + idx];
        const float wc = w[c];
        acc.x = fmaf(v.x, wc, acc.x);
        acc.y = fmaf(v.y, wc, acc.y);
        acc.z = fmaf(v.z, wc, acc.z);
        acc.w = fmaf(v.w, wc, acc.w);
    }
    ((float4*)out)[idx] = acc;
}

// ---------------------------------------------------------------------------

extern "C" void kernel_launch(void* const* d_in, const int* in_sizes, int n_in,
                              void* d_out, int out_size, void* d_ws, size_t ws_size,
                              hipStream_t stream) {
    const float* x      = (const float*)d_in[0];
    const float* wf1    = (const float*)d_in[1];
    const float* wf2    = (const float*)d_in[2];
    const float* wd1a   = (const float*)d_in[3];
    const float* wd1b   = (const float*)d_in[4];
    const float* wd2a   = (const float*)d_in[5];
    const float* wd2b   = (const float*)d_in[6];
    const float* wd3a   = (const float*)d_in[7];
    const float* wd3b   = (const float*)d_in[8];
    const float* wt1    = (const float*)d_in[9];
    const float* wu1a   = (const float*)d_in[10];
    const float* wu1b   = (const float*)d_in[11];
    const float* wt2    = (const float*)d_in[12];
    const float* wu2a   = (const float*)d_in[13];
    const float* wu2b   = (const float*)d_in[14];
    const float* wt3    = (const float*)d_in[15];
    const float* wu3a   = (const float*)d_in[16];
    const float* wu3b   = (const float*)d_in[17];
    const float* w_fin  = (const float*)d_in[18];
    const float* b_fin  = (const float*)d_in[19];
    float* out = (float*)d_out;

    const int V0 = 64 * 64 * 64;
    const int V1 = 32 * 32 * 32;
    const int V2 = 16 * 16 * 16;
    const int V3 = 8 * 8 * 8;

    float* ws    = (float*)d_ws;
    float* cat3  = ws;                         // 32 * V0   (x1 | up3)
    float* cat2  = cat3 + (size_t)32 * V0;     // 64 * V1   (x2 | up2)
    float* cat1  = cat2 + (size_t)64 * V1;     // 128 * V2  (x3 | up1)
    float* x4    = cat1 + (size_t)128 * V2;    // 128 * V3
    float* tA    = x4   + (size_t)128 * V3;    // 16 * V0
    float* tB    = tA   + (size_t)16 * V0;     // 16 * V0
    float* part  = tB   + (size_t)16 * V0;     // 16 * V0 = 16 MB (max S*Cout*V)
    float* stats = part + (size_t)16 * V0;     // 256
    float* pstat = stats + 256;                // 128*16*2

    auto blocks = [](int n) { return (n + 255) / 256; };

    auto bn_lrelu = [&](const float* p, float* dstp, int C, int V, int S) {
        const int NSEG = (V >= V0) ? 16 : (V == V1) ? 8 : (V == V2) ? 2 : 1;
        hipLaunchKernelGGL(bn_stats_part_v2, dim3(C, NSEG), dim3(256), 0, stream,
                           p, pstat, C, V, S, V / NSEG);
        hipLaunchKernelGGL(bn_stats_final, dim3(C), dim3(64), 0, stream, pstat, stats, NSEG, V);
        const int total4 = C * V / 4;
        hipLaunchKernelGGL(bn_apply_v3, dim3(blocks(total4)), dim3(256), 0, stream,
                           p, dstp, stats, C, V / 4, S, total4);
    };
    auto maxpool = [&](const float* in, float* o, int C, int D, int H, int W) {
        const int total = C * (D / 2) * (H / 2) * (W / 2);
        hipLaunchKernelGGL(maxpool_kernel, dim3(blocks(total)), dim3(256), 0, stream,
                           in, o, D, H, W, total);
    };

    // quad conv: grid (V/(4*BT), Cout/COB, CIN/CC)
#define CONVQ(CIN, CC, COB, BT, in_, wt_, dst_, Cout, D_, H_, W_)                           \
    {                                                                                       \
        const int V_ = (D_) * (H_) * (W_);                                                  \
        const int S  = (CIN) / (CC);                                                        \
        dim3 g(V_ / (4 * (BT)), (Cout) / (COB), S);                                         \
        hipLaunchKernelGGL((conv3_q<CIN, CC, COB, BT>), g, dim3(BT), 0, stream,             \
                           in_, wt_, part, D_, H_, W_);                                     \
        bn_lrelu(part, dst_, Cout, V_, S);                                                  \
    }
#define UPCONV(CIN, COB, VOXB, in_, wt_, dst_, Cout, Di_, Hi_, Wi_)                         \
    {                                                                                       \
        const int Vo_ = 8 * (Di_) * (Hi_) * (Wi_);                                          \
        dim3 g(Vo_ / (256 * (VOXB)), (Cout) / (COB));                                       \
        hipLaunchKernelGGL((upconv_v6<CIN, COB, VOXB>), g, dim3(256), 0, stream,            \
                           in_, wt_, dst_, Di_, Hi_, Wi_);                                  \
        bn_lrelu(dst_, dst_, Cout, Vo_, 1);                                                 \
    }

    // ----- encoder -----                                          blocks
    CONVQ(1,   1,  8, 256, x,   wf1,  tA,   16, 64, 64, 64);        // (256,2,1)=512
    CONVQ(16,  16, 4, 256, tA,  wf2,  cat3, 16, 64, 64, 64);        // (256,4,1)=1024
    maxpool(cat3, tA, 16, 64, 64, 64);
    CONVQ(16,  16, 2, 256, tA,  wd1a, tB,   32, 32, 32, 32);        // (32,16,1)=512
    CONVQ(32,  32, 2, 256, tB,  wd1b, cat2, 32, 32, 32, 32);        // (32,16,1)=512
    maxpool(cat2, tA, 32, 32, 32, 32);
    CONVQ(32,  8,  2, 256, tA,  wd2a, tB,   64, 16, 16, 16);        // (4,32,4)=512
    CONVQ(64,  8,  2, 256, tB,  wd2b, cat1, 64, 16, 16, 16);        // (4,32,8)=1024
    maxpool(cat1, tA, 64, 16, 16, 16);
    CONVQ(64,  8,  2, 128, tA,  wd3a, tB,  128, 8, 8, 8);           // (1,64,8)=512
    CONVQ(128, 16, 2, 128, tB,  wd3b, x4,  128, 8, 8, 8);           // (1,64,8)=512

    // ----- decoder -----
    UPCONV(128, 2, 1, x4, wt1, cat1 + (size_t)64 * V2, 64, 8, 8, 8);    // (16,32)=512
    CONVQ(128, 8, 2, 256, cat1, wu1a, tA, 64, 16, 16, 16);          // (4,32,16)=2048
    CONVQ(64,  8, 2, 256, tA,   wu1b, tB, 64, 16, 16, 16);          // (4,32,8)=1024

    UPCONV(64, 4, 1, tB, wt2, cat2 + (size_t)32 * V1, 32, 16, 16, 16);  // (128,8)=1024
    CONVQ(64, 32, 2, 256, cat2, wu2a, tA, 32, 32, 32, 32);          // (32,16,2)=1024
    CONVQ(32, 32, 2, 256, tA,   wu2b, tB, 32, 32, 32, 32);          // (32,16,1)=512

    UPCONV(32, 8, 4, tB, wt3, cat3 + (size_t)16 * V0, 16, 32, 32, 32);  // (256,2)=512
    CONVQ(32, 32, 4, 256, cat3, wu3a, tA, 16, 64, 64, 64);          // (256,4,1)=1024
    CONVQ(16, 16, 4, 256, tA,   wu3b, tB, 16, 64, 64, 64);          // (256,4,1)=1024

    // ----- final 1x1x1 conv + bias -----
    hipLaunchKernelGGL(final_v2, dim3(blocks(V0 / 4)), dim3(256), 0, stream,
                       tB, w_fin, b_fin, out, 16, V0 / 4);

#undef CONVQ
#undef UPCONV
}

// Round 8
// 1052.557 us; speedup vs baseline: 22.1426x; 1.6425x over previous
//
#include <hip/hip_runtime.h>

#define EPS   1e-5f
#define SLOPE 0.01f

// ---------------------------------------------------------------------------
// conv 3x3x3 pad=1 (cross-correlation), quad voxels + ci-split, grid-swapped.
// grid: (Cout/COB, V/(4*BT), CIN/CC)  -- co-block on x so same-voxel co-blocks
// are dispatch-adjacent (L2 reuse). Partials to part[z][co][v].
// Tap loops pinned unroll 1, ci loop unroll 4 (R4/R5: bound in-flight loads
// or the allocator explodes to 256 VGPR + scratch spills).
// ---------------------------------------------------------------------------
template <int CIN, int CC, int COB, int BT>
__global__ __launch_bounds__(BT) void conv3_q8(const float* __restrict__ in,
                                               const float* __restrict__ wt,
                                               float* __restrict__ part,
                                               int D, int H, int W) {
    const int V    = D * H * W;
    const int Cout = gridDim.x * COB;
    const int z    = blockIdx.z;
    const int cib  = z * CC;
    __shared__ float wlds[27 * CC * COB];
    const int co0 = blockIdx.x * COB;
    for (int i = threadIdx.x; i < 27 * CC * COB; i += BT) {
        const int tap = i / (CC * COB);
        const int r   = i - tap * (CC * COB);
        const int ci  = r / COB;
        const int co  = r - ci * COB;
        wlds[i] = wt[((size_t)(co0 + co) * CIN + cib + ci) * 27 + tap];
    }
    __syncthreads();

    const float* inz = in + (size_t)cib * V;
    const int v0 = (blockIdx.y * BT + threadIdx.x) * 4;
    const int w0 = v0 % W;
    const int h0 = (v0 / W) % H;
    const int d0 = v0 / (W * H);

    const bool mL = (w0 != 0);
    const bool mR = (w0 + 4 != W);
    const int  wl = w0 - (mL ? 1 : 0);
    const int  wr = w0 + (mR ? 4 : 3);

    float acc[COB * 4];
#pragma unroll
    for (int i = 0; i < COB * 4; ++i) acc[i] = 0.f;

#pragma unroll 1
    for (int kd = 0; kd < 3; ++kd) {
#pragma unroll 1
        for (int kh = 0; kh < 3; ++kh) {
            const int zd = d0 + kd - 1, zh = h0 + kh - 1;
            const bool okp = ((unsigned)zd < (unsigned)D) & ((unsigned)zh < (unsigned)H);
            const int row = okp ? (zd * H + zh) * W : 0;
            const float* wp0 = &wlds[((kd * 3 + kh) * 3 + 0) * CC * COB];
            const float* wp1 = wp0 + CC * COB;
            const float* wp2 = wp1 + CC * COB;
#pragma unroll 4
            for (int ci = 0; ci < CC; ++ci) {
                const float* p = inz + (size_t)ci * V + row;
                float4 m = *(const float4*)(p + w0);
                float lv = p[wl];
                float rv = p[wr];
                if (!okp) { m.x = 0.f; m.y = 0.f; m.z = 0.f; m.w = 0.f; }
                if (!(okp && mL)) lv = 0.f;
                if (!(okp && mR)) rv = 0.f;
#pragma unroll
                for (int co = 0; co < COB; ++co) {
                    const float a0 = wp0[ci * COB + co];
                    const float a1 = wp1[ci * COB + co];
                    const float a2 = wp2[ci * COB + co];
                    float* a = &acc[co * 4];
                    a[0] = fmaf(lv,  a0, fmaf(m.x, a1, fmaf(m.y, a2, a[0])));
                    a[1] = fmaf(m.x, a0, fmaf(m.y, a1, fmaf(m.z, a2, a[1])));
                    a[2] = fmaf(m.y, a0, fmaf(m.z, a1, fmaf(m.w, a2, a[2])));
                    a[3] = fmaf(m.z, a0, fmaf(m.w, a1, fmaf(rv,  a2, a[3])));
                }
            }
        }
    }
#pragma unroll
    for (int co = 0; co < COB; ++co)
        *(float4*)&part[((size_t)z * Cout + co0 + co) * V + v0] = *(const float4*)&acc[co * 4];
}

// ---------------------------------------------------------------------------
// upconv (NN-upsample x2 + circular 2x2x2 true convolution), ci-split, swapped.
// grid: (Cout/COB, Vo/(256*VOXB), CIN/CC)
// ---------------------------------------------------------------------------
template <int CIN, int CC, int COB, int VOXB>
__global__ __launch_bounds__(256) void upconv_v7(const float* __restrict__ in,
                                                 const float* __restrict__ wt,
                                                 float* __restrict__ part,
                                                 int Di, int Hi, int Wi) {
    const int Do = 2 * Di, Ho = 2 * Hi, Wo = 2 * Wi;
    const int Vo = Do * Ho * Wo;
    const int Vi = Di * Hi * Wi;
    const int Cout = gridDim.x * COB;
    const int z    = blockIdx.z;
    const int cib  = z * CC;
    __shared__ float wlds[8 * CC * COB];
    const int co0 = blockIdx.x * COB;
    for (int i = threadIdx.x; i < 8 * CC * COB; i += 256) {
        const int tap = i / (CC * COB);
        const int r   = i - tap * (CC * COB);
        const int ci  = r / COB;
        const int co  = r - ci * COB;
        wlds[i] = wt[((size_t)(co0 + co) * CIN + cib + ci) * 8 + tap];
    }
    __syncthreads();

    const float* inz = in + (size_t)cib * Vi;
    const int vbase = blockIdx.y * (256 * VOXB) + threadIdx.x;
    int od[VOXB], oh[VOXB], ow[VOXB];
#pragma unroll
    for (int j = 0; j < VOXB; ++j) {
        const int v = vbase + j * 256;
        ow[j] = v % Wo;
        oh[j] = (v / Wo) % Ho;
        od[j] = v / (Wo * Ho);
    }
    float acc[COB * VOXB];
#pragma unroll
    for (int i = 0; i < COB * VOXB; ++i) acc[i] = 0.f;

#pragma unroll 1
    for (int kd = 0; kd < 2; ++kd)
#pragma unroll 1
    for (int kh = 0; kh < 2; ++kh)
#pragma unroll
    for (int kw = 0; kw < 2; ++kw) {
        const int tap = (kd * 2 + kh) * 2 + kw;
        int sp[VOXB];
#pragma unroll
        for (int j = 0; j < VOXB; ++j) {
            const int id = ((od[j] - kd + Do) & (Do - 1)) >> 1;
            const int ih = ((oh[j] - kh + Ho) & (Ho - 1)) >> 1;
            const int iw = ((ow[j] - kw + Wo) & (Wo - 1)) >> 1;
            sp[j] = (id * Hi + ih) * Wi + iw;
        }
        const float* wrow = &wlds[tap * CC * COB];
#pragma unroll 4
        for (int ci = 0; ci < CC; ++ci) {
            float xv[VOXB];
#pragma unroll
            for (int j = 0; j < VOXB; ++j)
                xv[j] = inz[(size_t)ci * Vi + sp[j]];
            const float* wp = wrow + ci * COB;
#pragma unroll
            for (int co = 0; co < COB; ++co) {
                const float wgt = wp[co];
#pragma unroll
                for (int j = 0; j < VOXB; ++j)
                    acc[co * VOXB + j] = fmaf(xv[j], wgt, acc[co * VOXB + j]);
            }
        }
    }
#pragma unroll
    for (int co = 0; co < COB; ++co)
#pragma unroll
        for (int j = 0; j < VOXB; ++j)
            part[((size_t)z * Cout + co0 + co) * Vo + vbase + j * 256] = acc[co * VOXB + j];
}

// ---------------------------------------------------------------------------
// BN stats over split partials: pstat[c][seg] = (sum, sumsq) of sum_s part[s][c][.]
// ---------------------------------------------------------------------------
__global__ __launch_bounds__(256) void bn_stats_part_v2(const float* __restrict__ part,
                                                        float* __restrict__ pstat,
                                                        int C, int V, int S, int chunk) {
    const int c = blockIdx.x, seg = blockIdx.y;
    const size_t base = (size_t)c * V + (size_t)seg * chunk;
    float s1 = 0.f, s2 = 0.f;
    for (int i = threadIdx.x * 4; i < chunk; i += 1024) {
        float4 t = make_float4(0.f, 0.f, 0.f, 0.f);
        for (int s = 0; s < S; ++s) {
            const float4 v = *(const float4*)(part + (size_t)s * C * V + base + i);
            t.x += v.x; t.y += v.y; t.z += v.z; t.w += v.w;
        }
        s1 += t.x + t.y + t.z + t.w;
        s2 = fmaf(t.x, t.x, fmaf(t.y, t.y, fmaf(t.z, t.z, fmaf(t.w, t.w, s2))));
    }
#pragma unroll
    for (int off = 32; off > 0; off >>= 1) {
        s1 += __shfl_down(s1, off, 64);
        s2 += __shfl_down(s2, off, 64);
    }
    __shared__ float sh[8];
    const int wid  = threadIdx.x >> 6;
    const int lane = threadIdx.x & 63;
    if (lane == 0) { sh[wid] = s1; sh[4 + wid] = s2; }
    __syncthreads();
    if (threadIdx.x == 0) {
        pstat[(c * gridDim.y + seg) * 2]     = sh[0] + sh[1] + sh[2] + sh[3];
        pstat[(c * gridDim.y + seg) * 2 + 1] = sh[4] + sh[5] + sh[6] + sh[7];
    }
}

__global__ __launch_bounds__(64) void bn_stats_final(const float* __restrict__ pstat,
                                                     float* __restrict__ stats,
                                                     int S, int V) {
    const int c = blockIdx.x;
    float s1 = 0.f, s2 = 0.f;
    if ((int)threadIdx.x < S) {
        s1 = pstat[(c * S + threadIdx.x) * 2];
        s2 = pstat[(c * S + threadIdx.x) * 2 + 1];
    }
#pragma unroll
    for (int off = 32; off > 0; off >>= 1) {
        s1 += __shfl_down(s1, off, 64);
        s2 += __shfl_down(s2, off, 64);
    }
    if (threadIdx.x == 0) {
        const float inv  = 1.f / (float)V;
        const float mean = s1 * inv;
        const float var  = s2 * inv - mean * mean;
        stats[2 * c]     = mean;
        stats[2 * c + 1] = rsqrtf(var + EPS);
    }
}

// ---------------------------------------------------------------------------
// split-reduce + BN normalize + LeakyReLU: dst = lrelu((sum_s part[s] - m) * rstd)
// ---------------------------------------------------------------------------
__global__ __launch_bounds__(256) void bn_apply_v3(const float* __restrict__ part,
                                                   float* __restrict__ dst,
                                                   const float* __restrict__ stats,
                                                   int C, int V4, int S, int total4) {
    const int idx = blockIdx.x * blockDim.x + threadIdx.x;
    if (idx >= total4) return;
    const int c = idx / V4;
    const int v = idx - c * V4;
    const float4* p4 = (const float4*)part;
    float4 t = make_float4(0.f, 0.f, 0.f, 0.f);
    for (int s = 0; s < S; ++s) {
        const float4 x = p4[(size_t)(s * C + c) * V4 + v];
        t.x += x.x; t.y += x.y; t.z += x.z; t.w += x.w;
    }
    const float mean = stats[2 * c];
    const float rstd = stats[2 * c + 1];
    float u;
    u = (t.x - mean) * rstd; t.x = u >= 0.f ? u : SLOPE * u;
    u = (t.y - mean) * rstd; t.y = u >= 0.f ? u : SLOPE * u;
    u = (t.z - mean) * rstd; t.z = u >= 0.f ? u : SLOPE * u;
    u = (t.w - mean) * rstd; t.w = u >= 0.f ? u : SLOPE * u;
    ((float4*)dst)[idx] = t;
}

// ---------------------------------------------------------------------------
// 2x2x2 maxpool stride 2
// ---------------------------------------------------------------------------
__global__ __launch_bounds__(256) void maxpool_kernel(const float* __restrict__ in,
                                                      float* __restrict__ out,
                                                      int D, int H, int W, int total) {
    const int Do = D >> 1, Ho = H >> 1, Wo = W >> 1;
    const int Vo = Do * Ho * Wo;
    const int idx = blockIdx.x * blockDim.x + threadIdx.x;
    if (idx >= total) return;
    const int c  = idx / Vo;
    const int v  = idx - c * Vo;
    const int ow = v % Wo;
    const int oh = (v / Wo) % Ho;
    const int od = v / (Wo * Ho);
    const size_t HW = (size_t)H * W;
    const float* p = in + (size_t)c * D * HW + (size_t)(2 * od) * HW + (size_t)(2 * oh) * W + 2 * ow;
    float m = p[0];
    m = fmaxf(m, p[1]);
    m = fmaxf(m, p[W]);
    m = fmaxf(m, p[W + 1]);
    m = fmaxf(m, p[HW]);
    m = fmaxf(m, p[HW + 1]);
    m = fmaxf(m, p[HW + W]);
    m = fmaxf(m, p[HW + W + 1]);
    out[idx] = m;
}

// ---------------------------------------------------------------------------
// final 1x1x1 conv + bias, float4
// ---------------------------------------------------------------------------
__global__ __launch_bounds__(256) void final_v2(const float* __restrict__ in,
                                                const float* __restrict__ w,
                                                const float* __restrict__ b,
                                                float* __restrict__ out, int C, int V4) {
    const int idx = blockIdx.x * blockDim.x + threadIdx.x;
    if (idx >= V4) return;
    const float bb = b[0];
    float4 acc = make_float4(bb, bb, bb, bb);
    for (int c = 0; c < C; ++c) {
        const float4 v = ((const float4*)in)[(size_t)c * V4 + idx];
        const float wc = w[c];
        acc.x = fmaf(v.x, wc, acc.x);
        acc.y = fmaf(v.y, wc, acc.y);
        acc.z = fmaf(v.z, wc, acc.z);
        acc.w = fmaf(v.w, wc, acc.w);
    }
    ((float4*)out)[idx] = acc;
}

// ---------------------------------------------------------------------------

extern "C" void kernel_launch(void* const* d_in, const int* in_sizes, int n_in,
                              void* d_out, int out_size, void* d_ws, size_t ws_size,
                              hipStream_t stream) {
    const float* x      = (const float*)d_in[0];
    const float* wf1    = (const float*)d_in[1];
    const float* wf2    = (const float*)d_in[2];
    const float* wd1a   = (const float*)d_in[3];
    const float* wd1b   = (const float*)d_in[4];
    const float* wd2a   = (const float*)d_in[5];
    const float* wd2b   = (const float*)d_in[6];
    const float* wd3a   = (const float*)d_in[7];
    const float* wd3b   = (const float*)d_in[8];
    const float* wt1    = (const float*)d_in[9];
    const float* wu1a   = (const float*)d_in[10];
    const float* wu1b   = (const float*)d_in[11];
    const float* wt2    = (const float*)d_in[12];
    const float* wu2a   = (const float*)d_in[13];
    const float* wu2b   = (const float*)d_in[14];
    const float* wt3    = (const float*)d_in[15];
    const float* wu3a   = (const float*)d_in[16];
    const float* wu3b   = (const float*)d_in[17];
    const float* w_fin  = (const float*)d_in[18];
    const float* b_fin  = (const float*)d_in[19];
    float* out = (float*)d_out;

    const int V0 = 64 * 64 * 64;
    const int V1 = 32 * 32 * 32;
    const int V2 = 16 * 16 * 16;
    const int V3 = 8 * 8 * 8;

    float* ws    = (float*)d_ws;
    float* cat3  = ws;                         // 32 * V0   (x1 | up3)
    float* cat2  = cat3 + (size_t)32 * V0;     // 64 * V1   (x2 | up2)
    float* cat1  = cat2 + (size_t)64 * V1;     // 128 * V2  (x3 | up1)
    float* x4    = cat1 + (size_t)128 * V2;    // 128 * V3
    float* tA    = x4   + (size_t)128 * V3;    // 16 * V0
    float* tB    = tA   + (size_t)16 * V0;     // 16 * V0
    float* part  = tB   + (size_t)16 * V0;     // 16 * V0 (generic partial buffer)
    float* stats = part + (size_t)16 * V0;     // 256
    float* pstat = stats + 256;                // 128*16*2
    // Big-layer S=2 partials (need 32*V0) alias dead regions:
    //   tB..(tB+32V0)   == tB ∪ part      (tB free at wf2 / wu3a time)
    //   cat3 (32V0)                       (dead after wu3a consumes it)

    auto blocks = [](int n) { return (n + 255) / 256; };

    auto bn_lrelu = [&](const float* p, float* dstp, int C, int V, int S) {
        const int NSEG = (V >= V0) ? 16 : (V == V1) ? 8 : (V == V2) ? 2 : 1;
        hipLaunchKernelGGL(bn_stats_part_v2, dim3(C, NSEG), dim3(256), 0, stream,
                           p, pstat, C, V, S, V / NSEG);
        hipLaunchKernelGGL(bn_stats_final, dim3(C), dim3(64), 0, stream, pstat, stats, NSEG, V);
        const int total4 = C * V / 4;
        hipLaunchKernelGGL(bn_apply_v3, dim3(blocks(total4)), dim3(256), 0, stream,
                           p, dstp, stats, C, V / 4, S, total4);
    };
    auto maxpool = [&](const float* in, float* o, int C, int D, int H, int W) {
        const int total = C * (D / 2) * (H / 2) * (W / 2);
        hipLaunchKernelGGL(maxpool_kernel, dim3(blocks(total)), dim3(256), 0, stream,
                           in, o, D, H, W, total);
    };

    // conv: grid (Cout/COB, V/(4*BT), CIN/CC); partials to prt_, bn -> dst_
#define CONVQ(CIN, CC, COB, BT, in_, wt_, prt_, dst_, Cout, D_, H_, W_)                     \
    {                                                                                       \
        const int V_ = (D_) * (H_) * (W_);                                                  \
        const int S  = (CIN) / (CC);                                                        \
        dim3 g((Cout) / (COB), V_ / (4 * (BT)), S);                                         \
        hipLaunchKernelGGL((conv3_q8<CIN, CC, COB, BT>), g, dim3(BT), 0, stream,            \
                           in_, wt_, prt_, D_, H_, W_);                                     \
        bn_lrelu(prt_, dst_, Cout, V_, S);                                                  \
    }
#define UPCONV(CIN, CC, COB, VOXB, in_, wt_, prt_, dst_, Cout, Di_, Hi_, Wi_)               \
    {                                                                                       \
        const int Vo_ = 8 * (Di_) * (Hi_) * (Wi_);                                          \
        const int S  = (CIN) / (CC);                                                        \
        dim3 g((Cout) / (COB), Vo_ / (256 * (VOXB)), S);                                    \
        hipLaunchKernelGGL((upconv_v7<CIN, CC, COB, VOXB>), g, dim3(256), 0, stream,        \
                           in_, wt_, prt_, Di_, Hi_, Wi_);                                  \
        bn_lrelu(prt_, dst_, Cout, Vo_, S);                                                 \
    }

    // ----- encoder -----                                                  blocks
    CONVQ(1,   1,  8, 256, x,   wf1,  tA,   tA,          16, 64, 64, 64);   // (2,256,1)=512
    CONVQ(16,  8,  8, 256, tA,  wf2,  tB,   cat3,        16, 64, 64, 64);   // (2,256,2)=1024
    maxpool(cat3, tA, 16, 64, 64, 64);
    CONVQ(16,  8,  8, 64,  tA,  wd1a, part, tB,          32, 32, 32, 32);   // (4,128,2)=1024
    CONVQ(32,  8,  8, 64,  tB,  wd1b, part, cat2,        32, 32, 32, 32);   // (4,128,4)=2048
    maxpool(cat2, tA, 32, 32, 32, 32);
    CONVQ(32,  8,  8, 64,  tA,  wd2a, part, tB,          64, 16, 16, 16);   // (8,16,4)=512
    CONVQ(64,  8,  8, 64,  tB,  wd2b, part, cat1,        64, 16, 16, 16);   // (8,16,8)=1024
    maxpool(cat1, tA, 64, 16, 16, 16);
    CONVQ(64,  4,  8, 64,  tA,  wd3a, part, tB,         128, 8, 8, 8);      // (16,2,16)=512
    CONVQ(128, 8,  8, 64,  tB,  wd3b, part, x4,         128, 8, 8, 8);      // (16,2,16)=512

    // ----- decoder -----
    UPCONV(128, 16, 8, 1, x4, wt1, part, cat1 + (size_t)64 * V2, 64, 8, 8, 8);   // (8,16,8)=1024
    CONVQ(128, 8,  8, 64, cat1, wu1a, part, tA,          64, 16, 16, 16);   // (8,16,16)=2048
    CONVQ(64,  8,  8, 64, tA,   wu1b, part, tB,          64, 16, 16, 16);   // (8,16,8)=1024

    UPCONV(64, 16, 8, 1, tB, wt2, part, cat2 + (size_t)32 * V1, 32, 16, 16, 16); // (4,128,4)=2048
    CONVQ(64, 16, 8, 64, cat2, wu2a, part, tA,           32, 32, 32, 32);   // (4,128,4)=2048
    CONVQ(32, 8,  8, 64, tA,   wu2b, part, tB,           32, 32, 32, 32);   // (4,128,4)=2048

    {   // up3: S=1, write direct (part aliases dst; elementwise-safe)
        float* up3dst = cat3 + (size_t)16 * V0;
        UPCONV(32, 32, 8, 4, tB, wt3, up3dst, up3dst, 16, 32, 32, 32);      // (2,256,1)=512
    }
    CONVQ(32, 16, 8, 256, cat3, wu3a, tB,   tA,          16, 64, 64, 64);   // (2,256,2)=1024
    CONVQ(16, 8,  8, 256, tA,   wu3b, cat3, tB,          16, 64, 64, 64);   // (2,256,2)=1024

    // ----- final 1x1x1 conv + bias -----
    hipLaunchKernelGGL(final_v2, dim3(blocks(V0 / 4)), dim3(256), 0, stream,
                       tB, w_fin, b_fin, out, 16, V0 / 4);

#undef CONVQ
#undef UPCONV
}